// Round 16
// baseline (163.482 us; speedup 1.0000x reference)
//
#include <hip/hip_runtime.h>
#include <hip/hip_bf16.h>
#include <math.h>

// Problem geometry (B=2, T=1024, D=384 -> d=128, D3=384, D9=1152)
#define NTOK  2048
#define DD    128
#define DD3   384
#define DD9   1152
#define TB    2          // tokens per block in k_sig
#define TBQ   4          // tokens per block in k_qkv
#define TBP   4          // tokens per block in k_proj -> 512 blocks = 2/CU
#define GAMMA_F 5.0f
#define LN2_F   0.69314718f

// Workspace layout (float units):
#define OFF_M    0
#define OFF_C    147456
#define OFF_BP   148608
#define OFF_ATT  369792
#define OFF_SSUM 763008
#define OFF_QKV  765056

typedef __attribute__((ext_vector_type(2))) float f32x2;
typedef __attribute__((ext_vector_type(8))) short bf16x8;
typedef __attribute__((ext_vector_type(4))) float f32x4;

__device__ __forceinline__ float softplusf(float x) {
    return fmaxf(x, 0.0f) + log1pf(__expf(-fabsf(x)));
}
__device__ __forceinline__ unsigned short f2bf(float f) {
    __hip_bfloat16 h = __float2bfloat16(f);
    return *reinterpret_cast<unsigned short*>(&h);
}
__device__ __forceinline__ float bf2f(unsigned short u) {
    return __uint_as_float(((unsigned)u) << 16);
}

// ---- TRUE packed-f32 VOP3P ops (compiler scalarizes f32x2 elementwise builtins;
//      these halve the VALU instruction stream — the r8/r12/r15 flatness culprit)
#define PK_MUL(D, A, B) \
    asm("v_pk_mul_f32 %0, %1, %2" : "=v"(D) : "v"(A), "v"(B))
#define PK_FMA(D, A, B, C) \
    asm("v_pk_fma_f32 %0, %1, %2, %3" : "=v"(D) : "v"(A), "v"(B), "v"(C))
#define PK_FMA_ACC(D, A, B) /* D = A*B + D */ \
    asm("v_pk_fma_f32 %0, %1, %2, %0" : "+v"(D) : "v"(A), "v"(B))
#define PK_ADD_ACC(D, A)    /* D = D + A */ \
    asm("v_pk_add_f32 %0, %0, %1" : "+v"(D) : "v"(A))

// ---------------- prep: grid 963 x 384 (r13/r15-proven)
//  [0,576): B_pack   [576,960): M one (mat,i)/block   [960,963): c
__global__ __launch_bounds__(384) void k_prep(const float* __restrict__ Wq, const float* __restrict__ Wk,
                                              const float* __restrict__ Wv, const float* __restrict__ Wp,
                                              const float* __restrict__ Sq, const float* __restrict__ Sk,
                                              const float* __restrict__ Sv, const float* __restrict__ bq,
                                              const float* __restrict__ bk, const float* __restrict__ bv,
                                              float* __restrict__ ws) {
    __shared__ float sw[DD3];
    int b = blockIdx.x, tid = threadIdx.x;
    if (b < 576) {                        // ---- B_pack
        int idx = b * 384 + tid;
        unsigned lo = f2bf(softplusf(Wp[2 * idx + 0]) - LN2_F);
        unsigned hi = f2bf(softplusf(Wp[2 * idx + 1]) - LN2_F);
        ((unsigned*)(ws + OFF_BP))[idx] = lo | (hi << 16);
    } else if (b < 960) {                 // ---- M[i][m], interleaved-by-4 store
        int bb = b - 576;
        int mat = bb >> 7, i = bb & 127;
        const float* W = (mat == 0) ? Wq : (mat == 1 ? Wk : Wv);
        const float* S = (mat == 0) ? Sq : (mat == 1 ? Sk : Sv);
        int m = tid;
        sw[m] = softplusf(W[m * DD + i]);
        __syncthreads();
        const float4* sw4 = (const float4*)sw;
        float a0 = 0.f, a1 = 0.f, a2 = 0.f, a3 = 0.f;
        for (int j4 = 0; j4 < 96; ++j4) {
            float4 w = sw4[j4];
            int j = j4 * 4;
            a0 = fmaf(w.x, S[(j + 0) * DD3 + m], a0);
            a1 = fmaf(w.y, S[(j + 1) * DD3 + m], a1);
            a2 = fmaf(w.z, S[(j + 2) * DD3 + m], a2);
            a3 = fmaf(w.w, S[(j + 3) * DD3 + m], a3);
        }
        ws[OFF_M + mat * 49152 + (i >> 2) * (DD3 * 4) + m * 4 + (i & 3)] = (a0 + a1) + (a2 + a3);
    } else {                              // ---- c[m]
        int mat = b - 960;
        const float* S = (mat == 0) ? Sq : (mat == 1 ? Sk : Sv);
        const float* bb_ = (mat == 0) ? bq : (mat == 1 ? bk : bv);
        int m = tid;
        float a0 = 0.f, a1 = 0.f, a2 = 0.f, a3 = 0.f;
        for (int j4 = 0; j4 < 96; ++j4) {
            int j = j4 * 4;
            a0 = fmaf(bb_[j + 0], S[(j + 0) * DD3 + m], a0);
            a1 = fmaf(bb_[j + 1], S[(j + 1) * DD3 + m], a1);
            a2 = fmaf(bb_[j + 2], S[(j + 2) * DD3 + m], a2);
            a3 = fmaf(bb_[j + 3], S[(j + 3) * DD3 + m], a3);
        }
        ws[OFF_C + mat * DD3 + m] = (a0 + a1) + (a2 + a3);
    }
}

// Deg-13 odd Chebyshev tanh(3x) poly, all packed ops via VOP3P asm.
// Math order identical to r15 (med3 == min(max) on finite inputs).
#define PSIG(FQ2, K2, V2, RS2, AV2) do {                                      \
        f32x2 u_, w_, p_, s_, x_;                                              \
        PK_MUL(u_, FQ2, K2);                                                   \
        float cx_, cy_;                                                        \
        asm("v_med3_f32 %0, %1, -1.0, 1.0" : "=v"(cx_) : "v"(u_.x));           \
        asm("v_med3_f32 %0, %1, -1.0, 1.0" : "=v"(cy_) : "v"(u_.y));           \
        x_.x = cx_; x_.y = cy_;                                                \
        PK_MUL(w_, x_, x_);                                                    \
        PK_FMA(p_, PC13, w_, PC11);                                            \
        PK_FMA(p_, p_, w_, PC9);                                               \
        PK_FMA(p_, p_, w_, PC7);                                               \
        PK_FMA(p_, p_, w_, PC5);                                               \
        PK_FMA(p_, p_, w_, PC3);                                               \
        PK_FMA(p_, p_, w_, PC1);                                               \
        PK_FMA(s_, x_, p_, HALF2);                                             \
        PK_ADD_ACC(RS2, s_);                                                   \
        PK_FMA_ACC(AV2, s_, V2);                                               \
    } while (0)

#define PSIG_CONSTS                                                            \
    const f32x2 HALF2 = (f32x2){ 0.5f,  0.5f};                                 \
    const f32x2 PC1   = (f32x2){  1.4919730f,   1.4919730f};                   \
    const f32x2 PC3   = (f32x2){ -4.1350490f,  -4.1350490f};                   \
    const f32x2 PC5   = (f32x2){ 10.9501565f,  10.9501565f};                   \
    const f32x2 PC7   = (f32x2){-20.0847165f, -20.0847165f};                   \
    const f32x2 PC9   = (f32x2){ 22.6396415f,  22.6396415f};                   \
    const f32x2 PC11  = (f32x2){-13.8982400f, -13.8982400f};                   \
    const f32x2 PC13  = (f32x2){  3.5340290f,   3.5340290f};

// ---------------- split path A: QKV projection -> global fp32 (r15-verbatim)
__global__ __launch_bounds__(384, 3) void k_qkv(const float* __restrict__ x,
                                                float* __restrict__ ws) {
    int tid = threadIdx.x;
    int tok0 = blockIdx.x * TBQ;
    const float* xb = x + (size_t)tok0 * DD3;
    float* qg = ws + OFF_QKV + (size_t)tok0 * DD9;
#pragma unroll
    for (int mat = 0; mat < 3; ++mat) {
        const float4* M4 = (const float4*)(ws + OFF_M + mat * 49152);
        const float* xt0 = xb + 0 * DD3 + mat * DD;
        const float* xt1 = xb + 1 * DD3 + mat * DD;
        const float* xt2 = xb + 2 * DD3 + mat * DD;
        const float* xt3 = xb + 3 * DD3 + mat * DD;
        float a0 = 0.f, a1 = 0.f, a2 = 0.f, a3 = 0.f;
        for (int i4 = 0; i4 < 32; ++i4) {
            float4 mm = M4[i4 * DD3 + tid];
            int i = i4 * 4;
            a0 = fmaf(xt0[i], mm.x, fmaf(xt0[i + 1], mm.y, fmaf(xt0[i + 2], mm.z, fmaf(xt0[i + 3], mm.w, a0))));
            a1 = fmaf(xt1[i], mm.x, fmaf(xt1[i + 1], mm.y, fmaf(xt1[i + 2], mm.z, fmaf(xt1[i + 3], mm.w, a1))));
            a2 = fmaf(xt2[i], mm.x, fmaf(xt2[i + 1], mm.y, fmaf(xt2[i + 2], mm.z, fmaf(xt2[i + 3], mm.w, a2))));
            a3 = fmaf(xt3[i], mm.x, fmaf(xt3[i + 1], mm.y, fmaf(xt3[i + 2], mm.z, fmaf(xt3[i + 3], mm.w, a3))));
        }
        float c = ws[OFF_C + mat * DD3 + tid];
        qg[0 * DD9 + mat * DD3 + tid] = a0 + c;
        qg[1 * DD9 + mat * DD3 + tid] = a1 + c;
        qg[2 * DD9 + mat * DD3 + tid] = a2 + c;
        qg[3 * DD9 + mat * DD3 + tid] = a3 + c;
    }
}

// ---------------- split path B: sigmoid attention; K/V wave-uniform scalar loads
__global__ __launch_bounds__(384, 6) void k_sig(float* __restrict__ ws) {
    __shared__ float att[TB * DD3];
    __shared__ float red[16];
    int tid = threadIdx.x;
    int tok0 = blockIdx.x * TB;
    int t  = __builtin_amdgcn_readfirstlane(tid / 192);   // wave-uniform
    int ts = tid - t * 192;
    const float* qkvg = ws + OFF_QKV + (size_t)(tok0 + t) * DD9;

    PSIG_CONSTS
    float q0 = qkvg[ts]       * (GAMMA_F / 6.0f);
    float q1 = qkvg[ts + 192] * (GAMMA_F / 6.0f);
    f32x2 fq0 = (f32x2){q0, q0};
    f32x2 fq1 = (f32x2){q1, q1};
    const float4* K4 = (const float4*)(qkvg + DD3);       // uniform address
    const float4* V4 = (const float4*)(qkvg + 2 * DD3);
    f32x2 rs0 = (f32x2){0.f, 0.f}, rs1 = (f32x2){0.f, 0.f};
    f32x2 av0 = (f32x2){0.f, 0.f}, av1 = (f32x2){0.f, 0.f};
    for (int j4 = 0; j4 < 96; ++j4) {
        float4 kk = K4[j4];
        float4 vv = V4[j4];
        f32x2 kxy = (f32x2){kk.x, kk.y}, kzw = (f32x2){kk.z, kk.w};
        f32x2 vxy = (f32x2){vv.x, vv.y}, vzw = (f32x2){vv.z, vv.w};
        PSIG(fq0, kxy, vxy, rs0, av0);
        PSIG(fq0, kzw, vzw, rs0, av0);
        PSIG(fq1, kxy, vxy, rs1, av1);
        PSIG(fq1, kzw, vzw, rs1, av1);
    }
    float a0 = (av0.x + av0.y) * __builtin_amdgcn_rcpf(rs0.x + rs0.y + 1e-8f);
    float a1 = (av1.x + av1.y) * __builtin_amdgcn_rcpf(rs1.x + rs1.y + 1e-8f);
    unsigned short b0 = f2bf(a0), b1 = f2bf(a1);
    att[t * DD3 + ts]       = bf2f(b0);
    att[t * DD3 + ts + 192] = bf2f(b1);
    unsigned short* ag = (unsigned short*)(ws + OFF_ATT);
    ag[(size_t)(tok0 + t) * DD3 + ts]       = b0;
    ag[(size_t)(tok0 + t) * DD3 + ts + 192] = b1;
    __syncthreads();

    int wave = tid >> 6, lane64 = tid & 63;
    float s0 = att[0 * DD3 + tid];
    float s1 = att[1 * DD3 + tid];
#pragma unroll
    for (int off = 32; off; off >>= 1) {
        s0 += __shfl_down(s0, off, 64);
        s1 += __shfl_down(s1, off, 64);
    }
    if (lane64 == 0) { red[wave] = s0; red[8 + wave] = s1; }
    __syncthreads();
    if (tid < TB) {
        float a = 0.f;
        for (int w = 0; w < 6; ++w) a += red[tid * 8 + w];
        ws[OFF_SSUM + tok0 + tid] = a;
    }
}

// ---------------- k_proj: MFMA projection + LN (r15-verbatim, TBP=4)
__global__ __launch_bounds__(384, 3) void k_proj(const float* __restrict__ bp,
                                                 const float* __restrict__ gn,
                                                 const float* __restrict__ bn,
                                                 const float* __restrict__ ws,
                                                 float* __restrict__ out) {
    __shared__ unsigned short attb[16 * 392];
    __shared__ float h[TBP * DD9];
    __shared__ float red[32];
    __shared__ float smu[TBP], sinv[TBP];

    int tid = threadIdx.x;
    int wave = tid >> 6, lane64 = tid & 63;
    int tok0 = blockIdx.x * TBP;
    {
        const unsigned short* ag = (const unsigned short*)(ws + OFF_ATT) + (size_t)tok0 * DD3;
        if (tid < 192) {
            int r = tid / 48, c = (tid - r * 48) * 8;
            *(uint4*)(attb + r * 392 + c) = *(const uint4*)(ag + tid * 8);
        }
        unsigned* az = (unsigned*)(attb + 4 * 392);
        for (int idx = tid; idx < 2352; idx += 384) az[idx] = 0u;
    }
    __syncthreads();
    {
        int n0w  = wave * 192;
        int brow = lane64 & 15;
        int koff = (lane64 >> 4) * 8;
        const unsigned short* Bp = (const unsigned short*)(ws + OFF_BP);
        const unsigned short* abase = attb + brow * 392 + koff;
        const unsigned short* bbase = Bp + (size_t)(n0w + brow) * DD3 + koff;
        f32x4 acc[12];
#pragma unroll
        for (int nt = 0; nt < 12; ++nt) acc[nt] = (f32x4){0.f, 0.f, 0.f, 0.f};
        for (int ks = 0; ks < 12; ++ks) {
            bf16x8 a = *(const bf16x8*)(abase + ks * 32);
            const unsigned short* bk_ = bbase + ks * 32;
#pragma unroll
            for (int nt = 0; nt < 12; ++nt) {
                bf16x8 bfr = *(const bf16x8*)(bk_ + nt * 16 * DD3);
                acc[nt] = __builtin_amdgcn_mfma_f32_16x16x32_bf16(a, bfr, acc[nt], 0, 0, 0);
            }
        }
        if (lane64 < 16) {
            int col0 = n0w + lane64;
#pragma unroll
            for (int nt = 0; nt < 12; ++nt) {
#pragma unroll
                for (int r = 0; r < TBP; ++r)
                    h[r * DD9 + col0 + nt * 16] = acc[nt][r];
            }
        }
    }
    __syncthreads();

    const float* ssums = ws + OFF_SSUM + tok0;
    float acc3[3][TBP];
    {
        float bp0 = bp[tid], bp1 = bp[tid + DD3], bp2 = bp[tid + 2 * DD3];
#pragma unroll
        for (int t = 0; t < TBP; ++t) {
            float base = LN2_F * ssums[t];
            acc3[0][t] = h[t * DD9 + tid]           + bp0 + base;
            acc3[1][t] = h[t * DD9 + tid + DD3]     + bp1 + base;
            acc3[2][t] = h[t * DD9 + tid + 2 * DD3] + bp2 + base;
        }
    }
#pragma unroll
    for (int t = 0; t < TBP; ++t) {
        float s = acc3[0][t] + acc3[1][t] + acc3[2][t];
#pragma unroll
        for (int off = 32; off; off >>= 1) s += __shfl_down(s, off, 64);
        if (lane64 == 0) red[t * 8 + wave] = s;
    }
    __syncthreads();
    if (tid < TBP) {
        float a = 0.f;
        for (int w = 0; w < 6; ++w) a += red[tid * 8 + w];
        smu[tid] = a * (1.0f / 1152.0f);
    }
    __syncthreads();
#pragma unroll
    for (int t = 0; t < TBP; ++t) {
        float mu = smu[t];
        acc3[0][t] -= mu; acc3[1][t] -= mu; acc3[2][t] -= mu;
        float s = fmaf(acc3[0][t], acc3[0][t], fmaf(acc3[1][t], acc3[1][t], acc3[2][t] * acc3[2][t]));
#pragma unroll
        for (int off = 32; off; off >>= 1) s += __shfl_down(s, off, 64);
        if (lane64 == 0) red[t * 8 + wave] = s;
    }
    __syncthreads();
    if (tid < TBP) {
        float b = 0.f;
        for (int w = 0; w < 6; ++w) b += red[tid * 8 + w];
        sinv[tid] = __builtin_amdgcn_rsqf(b * (1.0f / 1152.0f) + 1e-5f);
    }
    __syncthreads();
    float g0 = gn[tid], g1 = gn[tid + DD3], g2 = gn[tid + 2 * DD3];
    float b0 = bn[tid], b1 = bn[tid + DD3], b2 = bn[tid + 2 * DD3];
#pragma unroll
    for (int t = 0; t < TBP; ++t) {
        float inv = sinv[t];
        size_t base = (size_t)(tok0 + t) * DD9;
        out[base + tid]           = fmaf(acc3[0][t] * inv, g0, b0);
        out[base + tid + DD3]     = fmaf(acc3[1][t] * inv, g1, b1);
        out[base + tid + 2 * DD3] = fmaf(acc3[2][t] * inv, g2, b2);
    }
}

extern "C" void kernel_launch(void* const* d_in, const int* in_sizes, int n_in,
                              void* d_out, int out_size, void* d_ws, size_t ws_size,
                              hipStream_t stream) {
    const float* x  = (const float*)d_in[0];
    const float* Wq = (const float*)d_in[1];
    const float* bq = (const float*)d_in[2];
    const float* Sq = (const float*)d_in[3];
    const float* Wk = (const float*)d_in[4];
    const float* bk = (const float*)d_in[5];
    const float* Sk = (const float*)d_in[6];
    const float* Wv = (const float*)d_in[7];
    const float* bv = (const float*)d_in[8];
    const float* Sv = (const float*)d_in[9];
    const float* Wp = (const float*)d_in[10];
    const float* bp = (const float*)d_in[11];
    const float* gn = (const float*)d_in[12];
    const float* bn = (const float*)d_in[13];
    float* out = (float*)d_out;
    float* ws  = (float*)d_ws;

    hipLaunchKernelGGL(k_prep, dim3(963), dim3(384), 0, stream,
                       Wq, Wk, Wv, Wp, Sq, Sk, Sv, bq, bk, bv, ws);
    hipLaunchKernelGGL(k_qkv, dim3(NTOK / TBQ), dim3(384), 0, stream, x, ws);
    hipLaunchKernelGGL(k_sig, dim3(NTOK / TB), dim3(384), 0, stream, ws);
    hipLaunchKernelGGL(k_proj, dim3(NTOK / TBP), dim3(384), 0, stream, bp, gn, bn, ws, out);
}

// Round 17
// 160.717 us; speedup vs baseline: 1.0172x; 1.0172x over previous
//
#include <hip/hip_runtime.h>
#include <hip/hip_bf16.h>
#include <math.h>

// Problem geometry (B=2, T=1024, D=384 -> d=128, D3=384, D9=1152)
#define NTOK  2048
#define DD    128
#define DD3   384
#define DD9   1152
#define TB    2          // tokens per block in k_sig
#define TBQ   4          // tokens per block in k_qkv
#define TBP   4          // tokens per block in k_proj -> 512 blocks = 2/CU
#define GAMMA_F 5.0f
#define LN2_F   0.69314718f
#define LOG2E_F 1.44269504f

// Workspace layout (float units):
#define OFF_M    0
#define OFF_C    147456
#define OFF_BP   148608
#define OFF_ATT  369792
#define OFF_SSUM 763008
#define OFF_QKV  765056

typedef __attribute__((ext_vector_type(8))) short bf16x8;
typedef __attribute__((ext_vector_type(4))) float f32x4;

__device__ __forceinline__ float softplusf(float x) {
    return fmaxf(x, 0.0f) + log1pf(__expf(-fabsf(x)));
}
__device__ __forceinline__ unsigned short f2bf(float f) {
    __hip_bfloat16 h = __float2bfloat16(f);
    return *reinterpret_cast<unsigned short*>(&h);
}
__device__ __forceinline__ float bf2f(unsigned short u) {
    return __uint_as_float(((unsigned)u) << 16);
}
__device__ __forceinline__ float exp2_fast(float x) {
#if __has_builtin(__builtin_amdgcn_exp2f)
    return __builtin_amdgcn_exp2f(x);
#else
    return __expf(x * LN2_F);
#endif
}

// ---------------- prep: grid 963 x 384 (r13/r15-proven)
//  [0,576): B_pack   [576,960): M one (mat,i)/block   [960,963): c
__global__ __launch_bounds__(384) void k_prep(const float* __restrict__ Wq, const float* __restrict__ Wk,
                                              const float* __restrict__ Wv, const float* __restrict__ Wp,
                                              const float* __restrict__ Sq, const float* __restrict__ Sk,
                                              const float* __restrict__ Sv, const float* __restrict__ bq,
                                              const float* __restrict__ bk, const float* __restrict__ bv,
                                              float* __restrict__ ws) {
    __shared__ float sw[DD3];
    int b = blockIdx.x, tid = threadIdx.x;
    if (b < 576) {                        // ---- B_pack
        int idx = b * 384 + tid;
        unsigned lo = f2bf(softplusf(Wp[2 * idx + 0]) - LN2_F);
        unsigned hi = f2bf(softplusf(Wp[2 * idx + 1]) - LN2_F);
        ((unsigned*)(ws + OFF_BP))[idx] = lo | (hi << 16);
    } else if (b < 960) {                 // ---- M[i][m], interleaved-by-4 store
        int bb = b - 576;
        int mat = bb >> 7, i = bb & 127;
        const float* W = (mat == 0) ? Wq : (mat == 1 ? Wk : Wv);
        const float* S = (mat == 0) ? Sq : (mat == 1 ? Sk : Sv);
        int m = tid;
        sw[m] = softplusf(W[m * DD + i]);
        __syncthreads();
        const float4* sw4 = (const float4*)sw;
        float a0 = 0.f, a1 = 0.f, a2 = 0.f, a3 = 0.f;
        for (int j4 = 0; j4 < 96; ++j4) {
            float4 w = sw4[j4];
            int j = j4 * 4;
            a0 = fmaf(w.x, S[(j + 0) * DD3 + m], a0);
            a1 = fmaf(w.y, S[(j + 1) * DD3 + m], a1);
            a2 = fmaf(w.z, S[(j + 2) * DD3 + m], a2);
            a3 = fmaf(w.w, S[(j + 3) * DD3 + m], a3);
        }
        ws[OFF_M + mat * 49152 + (i >> 2) * (DD3 * 4) + m * 4 + (i & 3)] = (a0 + a1) + (a2 + a3);
    } else {                              // ---- c[m]
        int mat = b - 960;
        const float* S = (mat == 0) ? Sq : (mat == 1 ? Sk : Sv);
        const float* bb_ = (mat == 0) ? bq : (mat == 1 ? bk : bv);
        int m = tid;
        float a0 = 0.f, a1 = 0.f, a2 = 0.f, a3 = 0.f;
        for (int j4 = 0; j4 < 96; ++j4) {
            int j = j4 * 4;
            a0 = fmaf(bb_[j + 0], S[(j + 0) * DD3 + m], a0);
            a1 = fmaf(bb_[j + 1], S[(j + 1) * DD3 + m], a1);
            a2 = fmaf(bb_[j + 2], S[(j + 2) * DD3 + m], a2);
            a3 = fmaf(bb_[j + 3], S[(j + 3) * DD3 + m], a3);
        }
        ws[OFF_C + mat * DD3 + m] = (a0 + a1) + (a2 + a3);
    }
}

// ---------------- split path A: QKV projection -> global fp32 (r15-verbatim)
__global__ __launch_bounds__(384, 3) void k_qkv(const float* __restrict__ x,
                                                float* __restrict__ ws) {
    int tid = threadIdx.x;
    int tok0 = blockIdx.x * TBQ;
    const float* xb = x + (size_t)tok0 * DD3;
    float* qg = ws + OFF_QKV + (size_t)tok0 * DD9;
#pragma unroll
    for (int mat = 0; mat < 3; ++mat) {
        const float4* M4 = (const float4*)(ws + OFF_M + mat * 49152);
        const float* xt0 = xb + 0 * DD3 + mat * DD;
        const float* xt1 = xb + 1 * DD3 + mat * DD;
        const float* xt2 = xb + 2 * DD3 + mat * DD;
        const float* xt3 = xb + 3 * DD3 + mat * DD;
        float a0 = 0.f, a1 = 0.f, a2 = 0.f, a3 = 0.f;
        for (int i4 = 0; i4 < 32; ++i4) {
            float4 mm = M4[i4 * DD3 + tid];
            int i = i4 * 4;
            a0 = fmaf(xt0[i], mm.x, fmaf(xt0[i + 1], mm.y, fmaf(xt0[i + 2], mm.z, fmaf(xt0[i + 3], mm.w, a0))));
            a1 = fmaf(xt1[i], mm.x, fmaf(xt1[i + 1], mm.y, fmaf(xt1[i + 2], mm.z, fmaf(xt1[i + 3], mm.w, a1))));
            a2 = fmaf(xt2[i], mm.x, fmaf(xt2[i + 1], mm.y, fmaf(xt2[i + 2], mm.z, fmaf(xt2[i + 3], mm.w, a2))));
            a3 = fmaf(xt3[i], mm.x, fmaf(xt3[i + 1], mm.y, fmaf(xt3[i + 2], mm.z, fmaf(xt3[i + 3], mm.w, a3))));
        }
        float c = ws[OFF_C + mat * DD3 + tid];
        qg[0 * DD9 + mat * DD3 + tid] = a0 + c;
        qg[1 * DD9 + mat * DD3 + tid] = a1 + c;
        qg[2 * DD9 + mat * DD3 + tid] = a2 + c;
        qg[3 * DD9 + mat * DD3 + tid] = a3 + c;
    }
}

// Exact sigmoid row-quad: 4 VALU/elem on main pipe + 2 trans/elem on the
// separate quarter-rate trans pipe (overlaps across waves). No clamp needed:
// exp2(+big)=inf -> rcp(1+inf)=0; exp2(-big)=0 -> s=1.
#define SIGROW(NQ, RS, AV) do {                                        \
        float e0 = exp2_fast((NQ) * kk.x);                             \
        float e1 = exp2_fast((NQ) * kk.y);                             \
        float e2 = exp2_fast((NQ) * kk.z);                             \
        float e3 = exp2_fast((NQ) * kk.w);                             \
        float s0 = __builtin_amdgcn_rcpf(1.0f + e0);                   \
        float s1 = __builtin_amdgcn_rcpf(1.0f + e1);                   \
        float s2 = __builtin_amdgcn_rcpf(1.0f + e2);                   \
        float s3 = __builtin_amdgcn_rcpf(1.0f + e3);                   \
        RS += (s0 + s1) + (s2 + s3);                                   \
        AV = fmaf(s0, vv.x, fmaf(s1, vv.y, fmaf(s2, vv.z, fmaf(s3, vv.w, AV)))); \
    } while (0)

// ---------------- split path B: sigmoid attention; K/V wave-uniform scalar loads
__global__ __launch_bounds__(384, 6) void k_sig(float* __restrict__ ws) {
    __shared__ float att[TB * DD3];
    __shared__ float red[16];
    int tid = threadIdx.x;
    int tok0 = blockIdx.x * TB;
    int t  = __builtin_amdgcn_readfirstlane(tid / 192);   // wave-uniform
    int ts = tid - t * 192;
    const float* qkvg = ws + OFF_QKV + (size_t)(tok0 + t) * DD9;

    float nq0 = qkvg[ts]       * (-GAMMA_F * LOG2E_F);
    float nq1 = qkvg[ts + 192] * (-GAMMA_F * LOG2E_F);
    const float4* K4 = (const float4*)(qkvg + DD3);       // uniform address -> s_load
    const float4* V4 = (const float4*)(qkvg + 2 * DD3);
    float rs0 = 0.f, rs1 = 0.f, av0 = 0.f, av1 = 0.f;
    for (int j4 = 0; j4 < 96; ++j4) {
        float4 kk = K4[j4];
        float4 vv = V4[j4];
        SIGROW(nq0, rs0, av0);
        SIGROW(nq1, rs1, av1);
    }
    float a0 = av0 * __builtin_amdgcn_rcpf(rs0 + 1e-8f);
    float a1 = av1 * __builtin_amdgcn_rcpf(rs1 + 1e-8f);
    unsigned short b0 = f2bf(a0), b1 = f2bf(a1);
    att[t * DD3 + ts]       = bf2f(b0);
    att[t * DD3 + ts + 192] = bf2f(b1);
    unsigned short* ag = (unsigned short*)(ws + OFF_ATT);
    ag[(size_t)(tok0 + t) * DD3 + ts]       = b0;
    ag[(size_t)(tok0 + t) * DD3 + ts + 192] = b1;
    __syncthreads();

    int wave = tid >> 6, lane64 = tid & 63;
    float s0 = att[0 * DD3 + tid];
    float s1 = att[1 * DD3 + tid];
#pragma unroll
    for (int off = 32; off; off >>= 1) {
        s0 += __shfl_down(s0, off, 64);
        s1 += __shfl_down(s1, off, 64);
    }
    if (lane64 == 0) { red[wave] = s0; red[8 + wave] = s1; }
    __syncthreads();
    if (tid < TB) {
        float a = 0.f;
        for (int w = 0; w < 6; ++w) a += red[tid * 8 + w];
        ws[OFF_SSUM + tok0 + tid] = a;
    }
}

// ---------------- k_proj: MFMA projection + LN (r15-verbatim, TBP=4)
__global__ __launch_bounds__(384, 3) void k_proj(const float* __restrict__ bp,
                                                 const float* __restrict__ gn,
                                                 const float* __restrict__ bn,
                                                 const float* __restrict__ ws,
                                                 float* __restrict__ out) {
    __shared__ unsigned short attb[16 * 392];
    __shared__ float h[TBP * DD9];
    __shared__ float red[32];
    __shared__ float smu[TBP], sinv[TBP];

    int tid = threadIdx.x;
    int wave = tid >> 6, lane64 = tid & 63;
    int tok0 = blockIdx.x * TBP;
    {
        const unsigned short* ag = (const unsigned short*)(ws + OFF_ATT) + (size_t)tok0 * DD3;
        if (tid < 192) {
            int r = tid / 48, c = (tid - r * 48) * 8;
            *(uint4*)(attb + r * 392 + c) = *(const uint4*)(ag + tid * 8);
        }
        unsigned* az = (unsigned*)(attb + 4 * 392);
        for (int idx = tid; idx < 2352; idx += 384) az[idx] = 0u;
    }
    __syncthreads();
    {
        int n0w  = wave * 192;
        int brow = lane64 & 15;
        int koff = (lane64 >> 4) * 8;
        const unsigned short* Bp = (const unsigned short*)(ws + OFF_BP);
        const unsigned short* abase = attb + brow * 392 + koff;
        const unsigned short* bbase = Bp + (size_t)(n0w + brow) * DD3 + koff;
        f32x4 acc[12];
#pragma unroll
        for (int nt = 0; nt < 12; ++nt) acc[nt] = (f32x4){0.f, 0.f, 0.f, 0.f};
        for (int ks = 0; ks < 12; ++ks) {
            bf16x8 a = *(const bf16x8*)(abase + ks * 32);
            const unsigned short* bk_ = bbase + ks * 32;
#pragma unroll
            for (int nt = 0; nt < 12; ++nt) {
                bf16x8 bfr = *(const bf16x8*)(bk_ + nt * 16 * DD3);
                acc[nt] = __builtin_amdgcn_mfma_f32_16x16x32_bf16(a, bfr, acc[nt], 0, 0, 0);
            }
        }
        if (lane64 < 16) {
            int col0 = n0w + lane64;
#pragma unroll
            for (int nt = 0; nt < 12; ++nt) {
#pragma unroll
                for (int r = 0; r < TBP; ++r)
                    h[r * DD9 + col0 + nt * 16] = acc[nt][r];
            }
        }
    }
    __syncthreads();

    const float* ssums = ws + OFF_SSUM + tok0;
    float acc3[3][TBP];
    {
        float bp0 = bp[tid], bp1 = bp[tid + DD3], bp2 = bp[tid + 2 * DD3];
#pragma unroll
        for (int t = 0; t < TBP; ++t) {
            float base = LN2_F * ssums[t];
            acc3[0][t] = h[t * DD9 + tid]           + bp0 + base;
            acc3[1][t] = h[t * DD9 + tid + DD3]     + bp1 + base;
            acc3[2][t] = h[t * DD9 + tid + 2 * DD3] + bp2 + base;
        }
    }
#pragma unroll
    for (int t = 0; t < TBP; ++t) {
        float s = acc3[0][t] + acc3[1][t] + acc3[2][t];
#pragma unroll
        for (int off = 32; off; off >>= 1) s += __shfl_down(s, off, 64);
        if (lane64 == 0) red[t * 8 + wave] = s;
    }
    __syncthreads();
    if (tid < TBP) {
        float a = 0.f;
        for (int w = 0; w < 6; ++w) a += red[tid * 8 + w];
        smu[tid] = a * (1.0f / 1152.0f);
    }
    __syncthreads();
#pragma unroll
    for (int t = 0; t < TBP; ++t) {
        float mu = smu[t];
        acc3[0][t] -= mu; acc3[1][t] -= mu; acc3[2][t] -= mu;
        float s = fmaf(acc3[0][t], acc3[0][t], fmaf(acc3[1][t], acc3[1][t], acc3[2][t] * acc3[2][t]));
#pragma unroll
        for (int off = 32; off; off >>= 1) s += __shfl_down(s, off, 64);
        if (lane64 == 0) red[t * 8 + wave] = s;
    }
    __syncthreads();
    if (tid < TBP) {
        float b = 0.f;
        for (int w = 0; w < 6; ++w) b += red[tid * 8 + w];
        sinv[tid] = __builtin_amdgcn_rsqf(b * (1.0f / 1152.0f) + 1e-5f);
    }
    __syncthreads();
    float g0 = gn[tid], g1 = gn[tid + DD3], g2 = gn[tid + 2 * DD3];
    float b0 = bn[tid], b1 = bn[tid + DD3], b2 = bn[tid + 2 * DD3];
#pragma unroll
    for (int t = 0; t < TBP; ++t) {
        float inv = sinv[t];
        size_t base = (size_t)(tok0 + t) * DD9;
        out[base + tid]           = fmaf(acc3[0][t] * inv, g0, b0);
        out[base + tid + DD3]     = fmaf(acc3[1][t] * inv, g1, b1);
        out[base + tid + 2 * DD3] = fmaf(acc3[2][t] * inv, g2, b2);
    }
}

extern "C" void kernel_launch(void* const* d_in, const int* in_sizes, int n_in,
                              void* d_out, int out_size, void* d_ws, size_t ws_size,
                              hipStream_t stream) {
    const float* x  = (const float*)d_in[0];
    const float* Wq = (const float*)d_in[1];
    const float* bq = (const float*)d_in[2];
    const float* Sq = (const float*)d_in[3];
    const float* Wk = (const float*)d_in[4];
    const float* bk = (const float*)d_in[5];
    const float* Sk = (const float*)d_in[6];
    const float* Wv = (const float*)d_in[7];
    const float* bv = (const float*)d_in[8];
    const float* Sv = (const float*)d_in[9];
    const float* Wp = (const float*)d_in[10];
    const float* bp = (const float*)d_in[11];
    const float* gn = (const float*)d_in[12];
    const float* bn = (const float*)d_in[13];
    float* out = (float*)d_out;
    float* ws  = (float*)d_ws;

    hipLaunchKernelGGL(k_prep, dim3(963), dim3(384), 0, stream,
                       Wq, Wk, Wv, Wp, Sq, Sk, Sv, bq, bk, bv, ws);
    hipLaunchKernelGGL(k_qkv, dim3(NTOK / TBQ), dim3(384), 0, stream, x, ws);
    hipLaunchKernelGGL(k_sig, dim3(NTOK / TB), dim3(384), 0, stream, ws);
    hipLaunchKernelGGL(k_proj, dim3(NTOK / TBP), dim3(384), 0, stream, bp, gn, bn, ws, out);
}

// Round 18
// 150.955 us; speedup vs baseline: 1.0830x; 1.0647x over previous
//
#include <hip/hip_runtime.h>
#include <hip/hip_bf16.h>
#include <math.h>

// Problem geometry (B=2, T=1024, D=384 -> d=128, D3=384, D9=1152)
#define NTOK  2048
#define DD    128
#define DD3   384
#define DD9   1152
#define TB    2          // tokens per block in k_sig
#define TBQ   2          // tokens per block in k_qkv -> 1024 blocks, 6 waves/SIMD
#define TBP   8          // tokens per block in k_proj -> 256 blocks
#define GAMMA_F 5.0f
#define LN2_F   0.69314718f
#define LOG2E_F 1.44269504f

// Workspace layout (float units):
#define OFF_M    0
#define OFF_C    147456
#define OFF_BP   148608
#define OFF_ATT  369792
#define OFF_QKV  765056

typedef __attribute__((ext_vector_type(8))) short bf16x8;
typedef __attribute__((ext_vector_type(4))) float f32x4;

__device__ __forceinline__ float softplusf(float x) {
    return fmaxf(x, 0.0f) + log1pf(__expf(-fabsf(x)));
}
__device__ __forceinline__ unsigned short f2bf(float f) {
    __hip_bfloat16 h = __float2bfloat16(f);
    return *reinterpret_cast<unsigned short*>(&h);
}
__device__ __forceinline__ float bf2f(unsigned short u) {
    return __uint_as_float(((unsigned)u) << 16);
}
__device__ __forceinline__ float exp2_fast(float x) {
#if __has_builtin(__builtin_amdgcn_exp2f)
    return __builtin_amdgcn_exp2f(x);
#else
    return __expf(x * LN2_F);
#endif
}

// ---------------- prep: grid 963 x 384 (r13/r17-proven)
__global__ __launch_bounds__(384) void k_prep(const float* __restrict__ Wq, const float* __restrict__ Wk,
                                              const float* __restrict__ Wv, const float* __restrict__ Wp,
                                              const float* __restrict__ Sq, const float* __restrict__ Sk,
                                              const float* __restrict__ Sv, const float* __restrict__ bq,
                                              const float* __restrict__ bk, const float* __restrict__ bv,
                                              float* __restrict__ ws) {
    __shared__ float sw[DD3];
    int b = blockIdx.x, tid = threadIdx.x;
    if (b < 576) {                        // ---- B_pack
        int idx = b * 384 + tid;
        unsigned lo = f2bf(softplusf(Wp[2 * idx + 0]) - LN2_F);
        unsigned hi = f2bf(softplusf(Wp[2 * idx + 1]) - LN2_F);
        ((unsigned*)(ws + OFF_BP))[idx] = lo | (hi << 16);
    } else if (b < 960) {                 // ---- M[i][m], interleaved-by-4 store
        int bb = b - 576;
        int mat = bb >> 7, i = bb & 127;
        const float* W = (mat == 0) ? Wq : (mat == 1 ? Wk : Wv);
        const float* S = (mat == 0) ? Sq : (mat == 1 ? Sk : Sv);
        int m = tid;
        sw[m] = softplusf(W[m * DD + i]);
        __syncthreads();
        const float4* sw4 = (const float4*)sw;
        float a0 = 0.f, a1 = 0.f, a2 = 0.f, a3 = 0.f;
        for (int j4 = 0; j4 < 96; ++j4) {
            float4 w = sw4[j4];
            int j = j4 * 4;
            a0 = fmaf(w.x, S[(j + 0) * DD3 + m], a0);
            a1 = fmaf(w.y, S[(j + 1) * DD3 + m], a1);
            a2 = fmaf(w.z, S[(j + 2) * DD3 + m], a2);
            a3 = fmaf(w.w, S[(j + 3) * DD3 + m], a3);
        }
        ws[OFF_M + mat * 49152 + (i >> 2) * (DD3 * 4) + m * 4 + (i & 3)] = (a0 + a1) + (a2 + a3);
    } else {                              // ---- c[m]
        int mat = b - 960;
        const float* S = (mat == 0) ? Sq : (mat == 1 ? Sk : Sv);
        const float* bb_ = (mat == 0) ? bq : (mat == 1 ? bk : bv);
        int m = tid;
        float a0 = 0.f, a1 = 0.f, a2 = 0.f, a3 = 0.f;
        for (int j4 = 0; j4 < 96; ++j4) {
            int j = j4 * 4;
            a0 = fmaf(bb_[j + 0], S[(j + 0) * DD3 + m], a0);
            a1 = fmaf(bb_[j + 1], S[(j + 1) * DD3 + m], a1);
            a2 = fmaf(bb_[j + 2], S[(j + 2) * DD3 + m], a2);
            a3 = fmaf(bb_[j + 3], S[(j + 3) * DD3 + m], a3);
        }
        ws[OFF_C + mat * DD3 + m] = (a0 + a1) + (a2 + a3);
    }
}

// ---------------- k_qkv: QKV projection, TBQ=2 at 6 waves/SIMD (occupancy fix)
__global__ __launch_bounds__(384, 6) void k_qkv(const float* __restrict__ x,
                                                float* __restrict__ ws) {
    int tid = threadIdx.x;
    int tok0 = blockIdx.x * TBQ;
    const float* xb = x + (size_t)tok0 * DD3;
    float* qg = ws + OFF_QKV + (size_t)tok0 * DD9;
#pragma unroll
    for (int mat = 0; mat < 3; ++mat) {
        const float4* M4 = (const float4*)(ws + OFF_M + mat * 49152);
        const float* xt0 = xb + 0 * DD3 + mat * DD;
        const float* xt1 = xb + 1 * DD3 + mat * DD;
        float a0 = 0.f, a1 = 0.f;
        for (int i4 = 0; i4 < 32; ++i4) {
            float4 mm = M4[i4 * DD3 + tid];
            int i = i4 * 4;
            a0 = fmaf(xt0[i], mm.x, fmaf(xt0[i + 1], mm.y, fmaf(xt0[i + 2], mm.z, fmaf(xt0[i + 3], mm.w, a0))));
            a1 = fmaf(xt1[i], mm.x, fmaf(xt1[i + 1], mm.y, fmaf(xt1[i + 2], mm.z, fmaf(xt1[i + 3], mm.w, a1))));
        }
        float c = ws[OFF_C + mat * DD3 + tid];
        qg[0 * DD9 + mat * DD3 + tid] = a0 + c;
        qg[1 * DD9 + mat * DD3 + tid] = a1 + c;
    }
}

// Exact sigmoid row-quad (r17-proven): 2 trans + ~4 VALU per element.
#define SIGROW(NQ, RS, AV) do {                                        \
        float e0 = exp2_fast((NQ) * kk.x);                             \
        float e1 = exp2_fast((NQ) * kk.y);                             \
        float e2 = exp2_fast((NQ) * kk.z);                             \
        float e3 = exp2_fast((NQ) * kk.w);                             \
        float s0 = __builtin_amdgcn_rcpf(1.0f + e0);                   \
        float s1 = __builtin_amdgcn_rcpf(1.0f + e1);                   \
        float s2 = __builtin_amdgcn_rcpf(1.0f + e2);                   \
        float s3 = __builtin_amdgcn_rcpf(1.0f + e3);                   \
        RS += (s0 + s1) + (s2 + s3);                                   \
        AV = fmaf(s0, vv.x, fmaf(s1, vv.y, fmaf(s2, vv.z, fmaf(s3, vv.w, AV)))); \
    } while (0)

// ---------------- k_sig: pure compute, no LDS, no barriers. Writes att bf16 only.
__global__ __launch_bounds__(384, 6) void k_sig(float* __restrict__ ws) {
    int tid = threadIdx.x;
    int tok0 = blockIdx.x * TB;
    int t  = __builtin_amdgcn_readfirstlane(tid / 192);   // wave-uniform
    int ts = tid - t * 192;
    const float* qkvg = ws + OFF_QKV + (size_t)(tok0 + t) * DD9;

    float nq0 = qkvg[ts]       * (-GAMMA_F * LOG2E_F);
    float nq1 = qkvg[ts + 192] * (-GAMMA_F * LOG2E_F);
    const float4* K4 = (const float4*)(qkvg + DD3);       // uniform -> s_load
    const float4* V4 = (const float4*)(qkvg + 2 * DD3);
    float rs0 = 0.f, rs1 = 0.f, av0 = 0.f, av1 = 0.f;
    for (int j4 = 0; j4 < 96; ++j4) {
        float4 kk = K4[j4];
        float4 vv = V4[j4];
        SIGROW(nq0, rs0, av0);
        SIGROW(nq1, rs1, av1);
    }
    float a0 = av0 * __builtin_amdgcn_rcpf(rs0 + 1e-8f);
    float a1 = av1 * __builtin_amdgcn_rcpf(rs1 + 1e-8f);
    unsigned short* ag = (unsigned short*)(ws + OFF_ATT);
    ag[(size_t)(tok0 + t) * DD3 + ts]       = f2bf(a0);
    ag[(size_t)(tok0 + t) * DD3 + ts + 192] = f2bf(a1);
}

// ---------------- k_proj: MFMA from GLOBAL A/B (no staging) + ssum + LN. TBP=8.
__global__ __launch_bounds__(384) void k_proj(const float* __restrict__ bp,
                                              const float* __restrict__ gn,
                                              const float* __restrict__ bn,
                                              const float* __restrict__ ws,
                                              float* __restrict__ out) {
    __shared__ float h[TBP * DD9];              // 36 KB
    __shared__ float red[64];
    __shared__ float ssum[TBP], smu[TBP], sinv[TBP];

    int tid = threadIdx.x;
    int wave = tid >> 6, lane64 = tid & 63;
    int tok0 = blockIdx.x * TBP;
    const unsigned short* ag = (const unsigned short*)(ws + OFF_ATT);

    // ---- ssum over the SAME bf16 att values the MFMA consumes (r6 consistency)
#pragma unroll
    for (int r = 0; r < TBP; ++r) {
        float s = bf2f(ag[(size_t)(tok0 + r) * DD3 + tid]);
#pragma unroll
        for (int off = 32; off; off >>= 1) s += __shfl_down(s, off, 64);
        if (lane64 == 0) red[r * 8 + wave] = s;
    }
    __syncthreads();
    if (tid < TBP) {
        float a = 0.f;
        for (int w = 0; w < 6; ++w) a += red[tid * 8 + w];
        ssum[tid] = a;
    }

    // ---- MFMA: A read directly from global (rows 8..15 alias rows 0..7 via brow&7;
    //      D rows 8..15 are never stored, so duplicates are harmless).
    {
        int n0w  = wave * 192;
        int brow = lane64 & 15;
        int koff = (lane64 >> 4) * 8;
        const unsigned short* Bp = (const unsigned short*)(ws + OFF_BP);
        const unsigned short* abase = ag + (size_t)(tok0 + (brow & 7)) * DD3 + koff;
        const unsigned short* bbase = Bp + (size_t)(n0w + brow) * DD3 + koff;
        f32x4 acc[12];
#pragma unroll
        for (int nt = 0; nt < 12; ++nt) acc[nt] = (f32x4){0.f, 0.f, 0.f, 0.f};
        for (int ks = 0; ks < 12; ++ks) {
            bf16x8 a = *(const bf16x8*)(abase + ks * 32);
            const unsigned short* bk_ = bbase + ks * 32;
#pragma unroll
            for (int nt = 0; nt < 12; ++nt) {
                bf16x8 bfr = *(const bf16x8*)(bk_ + nt * 16 * DD3);
                acc[nt] = __builtin_amdgcn_mfma_f32_16x16x32_bf16(a, bfr, acc[nt], 0, 0, 0);
            }
        }
        // C/D: col = lane&15, row = (lane>>4)*4 + reg. Rows 0..7 live in lanes 0..31.
        if (lane64 < 32) {
            int rbase = (lane64 >> 4) * 4;
            int col0  = n0w + (lane64 & 15);
#pragma unroll
            for (int nt = 0; nt < 12; ++nt) {
#pragma unroll
                for (int r = 0; r < 4; ++r)
                    h[(rbase + r) * DD9 + col0 + nt * 16] = acc[nt][r];
            }
        }
    }
    __syncthreads();

    // ---- bias + ln2*ssum fold, two-pass LayerNorm
    float acc3[3][TBP];
    {
        float bp0 = bp[tid], bp1 = bp[tid + DD3], bp2 = bp[tid + 2 * DD3];
#pragma unroll
        for (int t = 0; t < TBP; ++t) {
            float base = LN2_F * ssum[t];
            acc3[0][t] = h[t * DD9 + tid]           + bp0 + base;
            acc3[1][t] = h[t * DD9 + tid + DD3]     + bp1 + base;
            acc3[2][t] = h[t * DD9 + tid + 2 * DD3] + bp2 + base;
        }
    }
#pragma unroll
    for (int t = 0; t < TBP; ++t) {
        float s = acc3[0][t] + acc3[1][t] + acc3[2][t];
#pragma unroll
        for (int off = 32; off; off >>= 1) s += __shfl_down(s, off, 64);
        if (lane64 == 0) red[t * 8 + wave] = s;
    }
    __syncthreads();
    if (tid < TBP) {
        float a = 0.f;
        for (int w = 0; w < 6; ++w) a += red[tid * 8 + w];
        smu[tid] = a * (1.0f / 1152.0f);
    }
    __syncthreads();
#pragma unroll
    for (int t = 0; t < TBP; ++t) {
        float mu = smu[t];
        acc3[0][t] -= mu; acc3[1][t] -= mu; acc3[2][t] -= mu;
        float s = fmaf(acc3[0][t], acc3[0][t], fmaf(acc3[1][t], acc3[1][t], acc3[2][t] * acc3[2][t]));
#pragma unroll
        for (int off = 32; off; off >>= 1) s += __shfl_down(s, off, 64);
        if (lane64 == 0) red[t * 8 + wave] = s;
    }
    __syncthreads();
    if (tid < TBP) {
        float b = 0.f;
        for (int w = 0; w < 6; ++w) b += red[tid * 8 + w];
        sinv[tid] = __builtin_amdgcn_rsqf(b * (1.0f / 1152.0f) + 1e-5f);
    }
    __syncthreads();
    float g0 = gn[tid], g1 = gn[tid + DD3], g2 = gn[tid + 2 * DD3];
    float b0 = bn[tid], b1 = bn[tid + DD3], b2 = bn[tid + 2 * DD3];
#pragma unroll
    for (int t = 0; t < TBP; ++t) {
        float inv = sinv[t];
        size_t base = (size_t)(tok0 + t) * DD9;
        out[base + tid]           = fmaf(acc3[0][t] * inv, g0, b0);
        out[base + tid + DD3]     = fmaf(acc3[1][t] * inv, g1, b1);
        out[base + tid + 2 * DD3] = fmaf(acc3[2][t] * inv, g2, b2);
    }
}

extern "C" void kernel_launch(void* const* d_in, const int* in_sizes, int n_in,
                              void* d_out, int out_size, void* d_ws, size_t ws_size,
                              hipStream_t stream) {
    const float* x  = (const float*)d_in[0];
    const float* Wq = (const float*)d_in[1];
    const float* bq = (const float*)d_in[2];
    const float* Sq = (const float*)d_in[3];
    const float* Wk = (const float*)d_in[4];
    const float* bk = (const float*)d_in[5];
    const float* Sk = (const float*)d_in[6];
    const float* Wv = (const float*)d_in[7];
    const float* bv = (const float*)d_in[8];
    const float* Sv = (const float*)d_in[9];
    const float* Wp = (const float*)d_in[10];
    const float* bp = (const float*)d_in[11];
    const float* gn = (const float*)d_in[12];
    const float* bn = (const float*)d_in[13];
    float* out = (float*)d_out;
    float* ws  = (float*)d_ws;

    hipLaunchKernelGGL(k_prep, dim3(963), dim3(384), 0, stream,
                       Wq, Wk, Wv, Wp, Sq, Sk, Sv, bq, bk, bv, ws);
    hipLaunchKernelGGL(k_qkv, dim3(NTOK / TBQ), dim3(384), 0, stream, x, ws);
    hipLaunchKernelGGL(k_sig, dim3(NTOK / TB), dim3(384), 0, stream, ws);
    hipLaunchKernelGGL(k_proj, dim3(NTOK / TBP), dim3(384), 0, stream, bp, gn, bn, ws, out);
}